// Round 8
// baseline (489.160 us; speedup 1.0000x reference)
//
#include <hip/hip_runtime.h>
#include <hip/hip_bf16.h>

// Problem constants
#define NTOK 294                    // AGENT*WIN*WIN = 6*49
#define NB   256                    // X*Y = 16*16
#define NN   (NTOK*NTOK)            // 86436
#define ROWS_M (NB*NTOK)            // 75264
#define USN  19267584ULL            // 2048*294*32 ushorts per q/k/vt buffer
// ws: qb | kb | vt (bf16, USN each) | biasQ f32 (8*NN) | wqkvT bf16 | woutT bf16

typedef __bf16 bf16x8 __attribute__((ext_vector_type(8)));
typedef float  f32x4  __attribute__((ext_vector_type(4)));
typedef unsigned short ushort_t;

union Bf8 { bf16x8 v; unsigned short u[8]; };

__device__ inline unsigned short f2bf(float f) {      // RNE fp32 -> bf16
    unsigned int u = __float_as_uint(f);
    return (unsigned short)((u + 0x7FFFu + ((u >> 16) & 1u)) >> 16);
}

__device__ inline bf16x8 cvt8(float4 a, float4 b) {   // compiler emits v_cvt_pk_bf16_f32
    bf16x8 r;
    r[0] = (__bf16)a.x; r[1] = (__bf16)a.y; r[2] = (__bf16)a.z; r[3] = (__bf16)a.w;
    r[4] = (__bf16)b.x; r[5] = (__bf16)b.y; r[6] = (__bf16)b.z; r[7] = (__bf16)b.w;
    return r;
}

// ---------------- Kernel A: bias expand to [h][q][k] fp32 ----------------
__global__ void bias_expand(const float* __restrict__ table,
                            const int* __restrict__ rel,
                            float* __restrict__ biasQ) {
    int t = blockIdx.x * 256 + threadIdx.x;   // t = i*294 + j (q-major)
    if (t >= NN) return;
    int idx = rel[t];
    const float* src = table + idx * 8;
#pragma unroll
    for (int h = 0; h < 8; ++h)
        biasQ[h * NN + t] = src[h];
}

// ---------------- Kernel A2: weight transposes to bf16 [n][k] ------------
__global__ void wt_prep(const float* __restrict__ wqkv,
                        const float* __restrict__ wout,
                        ushort_t* __restrict__ wqkvT,
                        ushort_t* __restrict__ woutT) {
    int t = blockIdx.x * 256 + threadIdx.x;
    if (t < 768 * 256) {
        int n = t >> 8, k = t & 255;
        wqkvT[t] = f2bf(wqkv[k * 768 + n]);
    } else {
        int u = t - 768 * 256;
        int n = u >> 8, k = u & 255;
        woutT[u] = f2bf(wout[k * 256 + n]);
    }
}

// ---------------- Kernel B: LDS-free fused permute + QKV proj (MFMA) -----
// grid (6, 588): blockIdx.x = 128-col tile (temporally-adjacent blocks share
// the same x M-tile -> L2/L3 hit), blockIdx.y = 128-row tile.
// A-frag (row=lane&15, 8k consec) maps directly onto x row-major;
// B-frag maps directly onto wqkvT [n][k] bf16. No LDS, no barriers.
__global__ __launch_bounds__(256) void qkv_gemm_mfma2(const float* __restrict__ x,
                                                      const ushort_t* __restrict__ wqkvT,
                                                      ushort_t* __restrict__ qb,
                                                      ushort_t* __restrict__ kb,
                                                      ushort_t* __restrict__ vt) {
    const int t    = threadIdx.x;
    const int lane = t & 63;
    const int w    = t >> 6;
    const int wm   = w >> 1, wn = w & 1;
    const int l15  = lane & 15, kg8 = (lane >> 4) * 8;
    const int cb   = blockIdx.x * 128;
    const int mt   = blockIdx.y * 128;

    // per-lane A row pointers (permuted x addressing)
    const float* arow[4];
#pragma unroll
    for (int fi = 0; fi < 4; ++fi) {
        int m  = mt + wm * 64 + fi * 16 + l15;
        int Bi = m / NTOK, n = m - Bi * NTOK;
        int l  = n / 49,   ww = n - l * 49;
        int xx = Bi >> 4,  yy = Bi & 15;
        arow[fi] = x + (size_t)((((l * 16 + xx) * 16 + yy) * 49 + ww) << 8) + kg8;
    }
    // per-lane B row pointers (wqkvT [768][256])
    const ushort_t* brow[4];
#pragma unroll
    for (int fj = 0; fj < 4; ++fj) {
        int nn = cb + wn * 64 + fj * 16 + l15;
        brow[fj] = wqkvT + (size_t)nn * 256 + kg8;
    }

    f32x4 acc[4][4];
#pragma unroll
    for (int i = 0; i < 4; ++i)
#pragma unroll
        for (int j = 0; j < 4; ++j) acc[i][j] = (f32x4){0.f, 0.f, 0.f, 0.f};

#pragma unroll 2
    for (int kk = 0; kk < 256; kk += 32) {
        bf16x8 af[4], bfr[4];
#pragma unroll
        for (int fi = 0; fi < 4; ++fi) {
            float4 f0 = *(const float4*)(arow[fi] + kk);
            float4 f1 = *(const float4*)(arow[fi] + kk + 4);
            af[fi] = cvt8(f0, f1);
        }
#pragma unroll
        for (int fj = 0; fj < 4; ++fj)
            bfr[fj] = *(const bf16x8*)(brow[fj] + kk);
#pragma unroll
        for (int fi = 0; fi < 4; ++fi)
#pragma unroll
            for (int fj = 0; fj < 4; ++fj)
                acc[fi][fj] = __builtin_amdgcn_mfma_f32_16x16x32_bf16(
                    af[fi], bfr[fj], acc[fi][fj], 0, 0, 0);
    }

    // epilogue: scatter to q(scaled)/k/vt bf16 (layouts unchanged, verified)
    const float scale = 0.17677669529663687f;  // dh^-0.5
    const int rq   = lane >> 4;
    const int cidx = lane & 15;
#pragma unroll
    for (int fi = 0; fi < 4; ++fi) {
#pragma unroll
        for (int reg = 0; reg < 4; ++reg) {
            int mm  = mt + wm * 64 + fi * 16 + rq * 4 + reg;
            int Bi2 = mm / NTOK, n2 = mm - Bi2 * NTOK;
#pragma unroll
            for (int fj = 0; fj < 4; ++fj) {
                int c     = cb + wn * 64 + fj * 16 + cidx;
                int which = c >> 8;
                int rr    = c & 255;
                int hh    = rr >> 5, di = rr & 31;
                int bhi   = Bi2 * 8 + hh;
                if (which == 0) {
                    qb[((size_t)bhi * NTOK + n2) * 32 + di] = f2bf(acc[fi][fj][reg] * scale);
                } else if (which == 1) {
                    kb[((size_t)bhi * NTOK + n2) * 32 + di] = f2bf(acc[fi][fj][reg]);
                } else {
                    vt[((size_t)bhi * 32 + di) * NTOK + n2] = f2bf(acc[fi][fj][reg]);
                }
            }
        }
    }
}

// ---------------- Kernel C: MFMA flash attention (unchanged, verified) ---
#define S_KS 40
#define S_VS 328
#define S_PS 40
__global__ __launch_bounds__(256) void attn_mfma(ushort_t* __restrict__ qb,
                                                 const ushort_t* __restrict__ kb,
                                                 const ushort_t* __restrict__ vt,
                                                 const float* __restrict__ biasQ) {
    __shared__ ushort_t ks[320 * S_KS];
    __shared__ ushort_t vs[32 * S_VS];
    __shared__ ushort_t ps[4 * 16 * S_PS];
    const int qt = blockIdx.x, bh = blockIdx.y, h = bh & 7;
    const int tid = threadIdx.x;

    const unsigned int* ksrc = (const unsigned int*)(kb + (size_t)bh * NTOK * 32);
    for (int t = tid; t < 294 * 16; t += 256) {
        int r = t >> 4, i = t & 15;
        *(unsigned int*)&ks[r * S_KS + 2 * i] = ksrc[t];
    }
    for (int t = tid; t < 26 * 16; t += 256) {
        int r = 294 + (t >> 4), i = t & 15;
        *(unsigned int*)&ks[r * S_KS + 2 * i] = 0u;
    }
    const unsigned int* vsrc = (const unsigned int*)(vt + (size_t)bh * 32 * NTOK);
    for (int t = tid; t < 32 * 147; t += 256) {
        int d = t / 147, i = t - d * 147;
        *(unsigned int*)&vs[d * S_VS + 2 * i] = vsrc[t];
    }
    for (int t = tid; t < 32 * 17; t += 256) {
        int d = t / 17, i = 147 + (t - d * 17);
        *(unsigned int*)&vs[d * S_VS + 2 * i] = 0u;
    }
    __syncthreads();

    const int wave = tid >> 6, lane = tid & 63;
    const int c = lane & 15, g = lane >> 4;
    const int q0 = qt * 128 + wave * 32;

    bf16x8 qf[2];
#pragma unroll
    for (int qs = 0; qs < 2; ++qs) {
        int qa = q0 + qs * 16 + c; if (qa > 293) qa = 293;
        qf[qs] = *(const bf16x8*)&qb[((size_t)bh * NTOK + qa) * 32 + 8 * g];
    }
    f32x4 acc_o[2][2];
    float psum[2][4];
#pragma unroll
    for (int qs = 0; qs < 2; ++qs) {
#pragma unroll
        for (int hf = 0; hf < 2; ++hf) acc_o[qs][hf] = (f32x4){0.f, 0.f, 0.f, 0.f};
#pragma unroll
        for (int rg = 0; rg < 4; ++rg) psum[qs][rg] = 0.f;
    }
    ushort_t* pw = ps + wave * 16 * S_PS;
    const float* bbase = biasQ + (size_t)h * NN;

    for (int kt = 0; kt < 10; ++kt) {
        const int kbase = kt * 32;
        bf16x8 kf[2], vf[2];
#pragma unroll
        for (int ksub = 0; ksub < 2; ++ksub)
            kf[ksub] = *(const bf16x8*)&ks[(kbase + ksub * 16 + c) * S_KS + 8 * g];
#pragma unroll
        for (int hf = 0; hf < 2; ++hf)
            vf[hf] = *(const bf16x8*)&vs[(hf * 16 + c) * S_VS + kbase + 8 * g];

#pragma unroll
        for (int qs = 0; qs < 2; ++qs) {
            f32x4 s0 = __builtin_amdgcn_mfma_f32_16x16x32_bf16(
                qf[qs], kf[0], (f32x4){0.f, 0.f, 0.f, 0.f}, 0, 0, 0);
            f32x4 s1 = __builtin_amdgcn_mfma_f32_16x16x32_bf16(
                qf[qs], kf[1], (f32x4){0.f, 0.f, 0.f, 0.f}, 0, 0, 0);
            const int qrb = q0 + qs * 16 + g * 4;
#pragma unroll
            for (int rg = 0; rg < 4; ++rg) {
                int qa = qrb + rg; if (qa > 293) qa = 293;
                const float* bp = bbase + (size_t)qa * NTOK;
#pragma unroll
                for (int ksub = 0; ksub < 2; ++ksub) {
                    int ka = kbase + ksub * 16 + c;
                    int kc = ka > 293 ? 293 : ka;
                    float bias = (ka < NTOK) ? bp[kc] : -1e4f;
                    float s = (ksub ? s1[rg] : s0[rg]) + bias;
                    float p = __expf(s);
                    psum[qs][rg] += p;
                    pw[(g * 4 + rg) * S_PS + ksub * 16 + c] = f2bf(p);
                }
            }
            bf16x8 pa = *(const bf16x8*)&pw[c * S_PS + 8 * g];
#pragma unroll
            for (int hf = 0; hf < 2; ++hf)
                acc_o[qs][hf] = __builtin_amdgcn_mfma_f32_16x16x32_bf16(
                    pa, vf[hf], acc_o[qs][hf], 0, 0, 0);
        }
    }

#pragma unroll
    for (int qs = 0; qs < 2; ++qs)
#pragma unroll
        for (int rg = 0; rg < 4; ++rg) {
            float v = psum[qs][rg];
            v += __shfl_xor(v, 1); v += __shfl_xor(v, 2);
            v += __shfl_xor(v, 4); v += __shfl_xor(v, 8);
            psum[qs][rg] = 1.0f / v;
        }

#pragma unroll
    for (int qs = 0; qs < 2; ++qs) {
        const int qrb = q0 + qs * 16 + g * 4;
#pragma unroll
        for (int rg = 0; rg < 4; ++rg) {
            int qa = qrb + rg;
            if (qa < NTOK) {
#pragma unroll
                for (int hf = 0; hf < 2; ++hf) {
                    float val = acc_o[qs][hf][rg] * psum[qs][rg];
                    qb[((size_t)bh * NTOK + qa) * 32 + hf * 16 + c] = f2bf(val);
                }
            }
        }
    }
}

// ---------------- Kernel D: LDS-free out projection + inverse permute ----
// grid (2, 588). A = ob bf16 [bh][n][32] read directly as fragments;
// B = woutT bf16 [256][256].
__global__ __launch_bounds__(256) void out_gemm_mfma2(const ushort_t* __restrict__ ob,
                                                      const ushort_t* __restrict__ woutT,
                                                      float* __restrict__ out) {
    const int t    = threadIdx.x;
    const int lane = t & 63;
    const int w    = t >> 6;
    const int wm   = w >> 1, wn = w & 1;
    const int l15  = lane & 15, kg8 = (lane >> 4) * 8;
    const int cb   = blockIdx.x * 128;
    const int mt   = blockIdx.y * 128;

    // per-lane A base (k=0 head): + (kk>>5)*NTOK*32 per K-step
    const ushort_t* abase[4];
#pragma unroll
    for (int fi = 0; fi < 4; ++fi) {
        int m  = mt + wm * 64 + fi * 16 + l15;
        int Bi = m / NTOK, n = m - Bi * NTOK;
        abase[fi] = ob + ((size_t)(Bi * 8) * NTOK + n) * 32 + kg8;
    }
    const ushort_t* brow[4];
#pragma unroll
    for (int fj = 0; fj < 4; ++fj) {
        int nn = cb + wn * 64 + fj * 16 + l15;
        brow[fj] = woutT + (size_t)nn * 256 + kg8;
    }

    f32x4 acc[4][4];
#pragma unroll
    for (int i = 0; i < 4; ++i)
#pragma unroll
        for (int j = 0; j < 4; ++j) acc[i][j] = (f32x4){0.f, 0.f, 0.f, 0.f};

#pragma unroll 2
    for (int kk = 0; kk < 256; kk += 32) {
        const int hstep = kk >> 5;
        bf16x8 af[4], bfr[4];
#pragma unroll
        for (int fi = 0; fi < 4; ++fi)
            af[fi] = *(const bf16x8*)(abase[fi] + (size_t)hstep * NTOK * 32);
#pragma unroll
        for (int fj = 0; fj < 4; ++fj)
            bfr[fj] = *(const bf16x8*)(brow[fj] + kk);
#pragma unroll
        for (int fi = 0; fi < 4; ++fi)
#pragma unroll
            for (int fj = 0; fj < 4; ++fj)
                acc[fi][fj] = __builtin_amdgcn_mfma_f32_16x16x32_bf16(
                    af[fi], bfr[fj], acc[fi][fj], 0, 0, 0);
    }

    const int rq   = lane >> 4;
    const int cidx = lane & 15;
#pragma unroll
    for (int fi = 0; fi < 4; ++fi) {
#pragma unroll
        for (int reg = 0; reg < 4; ++reg) {
            int mm  = mt + wm * 64 + fi * 16 + rq * 4 + reg;
            int Bi2 = mm / NTOK, n2 = mm - Bi2 * NTOK;
            int l2  = n2 / 49,   w2 = n2 - l2 * 49;
            int xx2 = Bi2 >> 4,  yy2 = Bi2 & 15;
            float* orow = out + (size_t)((((l2 * 16 + xx2) * 16 + yy2) * 49 + w2) << 8);
#pragma unroll
            for (int fj = 0; fj < 4; ++fj) {
                int c = cb + wn * 64 + fj * 16 + cidx;
                orow[c] = acc[fi][fj][reg];
            }
        }
    }
}

extern "C" void kernel_launch(void* const* d_in, const int* in_sizes, int n_in,
                              void* d_out, int out_size, void* d_ws, size_t ws_size,
                              hipStream_t stream) {
    const float* x     = (const float*)d_in[0];
    const float* wqkv  = (const float*)d_in[1];
    const float* wout  = (const float*)d_in[2];
    const float* table = (const float*)d_in[3];
    const int*   rel   = (const int*)d_in[4];
    float* out = (float*)d_out;

    ushort_t* qb    = (ushort_t*)d_ws;
    ushort_t* kb    = qb + USN;
    ushort_t* vt    = kb + USN;
    float*    biasQ = (float*)(vt + USN);         // 8*NN floats
    ushort_t* wqkvT = (ushort_t*)(biasQ + 8 * NN); // 768*256
    ushort_t* woutT = wqkvT + 768 * 256;           // 256*256

    hipLaunchKernelGGL(bias_expand, dim3((NN + 255) / 256), dim3(256), 0, stream,
                       table, rel, biasQ);
    hipLaunchKernelGGL(wt_prep, dim3((768 * 256 + 256 * 256) / 256), dim3(256), 0, stream,
                       wqkv, wout, wqkvT, woutT);
    hipLaunchKernelGGL(qkv_gemm_mfma2, dim3(6, 588), dim3(256), 0, stream,
                       x, wqkvT, qb, kb, vt);
    hipLaunchKernelGGL(attn_mfma, dim3(3, 2048), dim3(256), 0, stream,
                       qb, kb, vt, biasQ);
    hipLaunchKernelGGL(out_gemm_mfma2, dim3(2, 588), dim3(256), 0, stream,
                       qb, woutT, out);
}

// Round 9
// 474.735 us; speedup vs baseline: 1.0304x; 1.0304x over previous
//
#include <hip/hip_runtime.h>
#include <hip/hip_bf16.h>

// Problem constants
#define NTOK 294                    // AGENT*WIN*WIN = 6*49
#define NB   256                    // X*Y = 16*16
#define NN   (NTOK*NTOK)            // 86436
#define ROWS_M (NB*NTOK)            // 75264
#define USN  19267584ULL            // 2048*294*32 ushorts per q/k/vt buffer
// ws: qb | kb | vt (bf16, USN each) | biasQ f32 (8*NN) | wqkvT bf16 | woutT bf16

typedef __bf16 bf16x8 __attribute__((ext_vector_type(8)));
typedef float  f32x4  __attribute__((ext_vector_type(4)));
typedef unsigned short ushort_t;

union Bf8 { bf16x8 v; unsigned short u[8]; };

__device__ inline unsigned short f2bf(float f) {      // RNE fp32 -> bf16
    unsigned int u = __float_as_uint(f);
    return (unsigned short)((u + 0x7FFFu + ((u >> 16) & 1u)) >> 16);
}

__device__ inline bf16x8 cvt8(float4 a, float4 b) {
    bf16x8 r;
    r[0] = (__bf16)a.x; r[1] = (__bf16)a.y; r[2] = (__bf16)a.z; r[3] = (__bf16)a.w;
    r[4] = (__bf16)b.x; r[5] = (__bf16)b.y; r[6] = (__bf16)b.z; r[7] = (__bf16)b.w;
    return r;
}

// ---------------- Kernel A: bias expand to [h][q][k] fp32 ----------------
__global__ void bias_expand(const float* __restrict__ table,
                            const int* __restrict__ rel,
                            float* __restrict__ biasQ) {
    int t = blockIdx.x * 256 + threadIdx.x;   // t = i*294 + j (q-major)
    if (t >= NN) return;
    int idx = rel[t];
    const float* src = table + idx * 8;
#pragma unroll
    for (int h = 0; h < 8; ++h)
        biasQ[h * NN + t] = src[h];
}

// ---------------- Kernel A2: weight transposes to bf16 [n][k] ------------
__global__ void wt_prep(const float* __restrict__ wqkv,
                        const float* __restrict__ wout,
                        ushort_t* __restrict__ wqkvT,
                        ushort_t* __restrict__ woutT) {
    int t = blockIdx.x * 256 + threadIdx.x;
    if (t < 768 * 256) {
        int n = t >> 8, k = t & 255;
        wqkvT[t] = f2bf(wqkv[k * 768 + n]);
    } else {
        int u = t - 768 * 256;
        int n = u >> 8, k = u & 255;
        woutT[u] = f2bf(wout[k * 256 + n]);
    }
}

// ---------------- Kernel B: A-staged-once QKV projection (bf16 MFMA) -----
// grid 588: one block per 128-row tile. A [128][256] bf16 staged ONCE in LDS
// (XOR-swizzled, 64 KB); then 6 column tiles with B-fragments read directly
// from L2-resident wqkvT (393 KB). No barriers inside the compute loop.
// A is fetched from HBM exactly once -> XCD-placement-independent reuse.
__global__ __launch_bounds__(256) void qkv_gemm_mfma3(const float* __restrict__ x,
                                                      const ushort_t* __restrict__ wqkvT,
                                                      ushort_t* __restrict__ qb,
                                                      ushort_t* __restrict__ kb,
                                                      ushort_t* __restrict__ vt) {
    __shared__ ushort_t As[128 * 256];   // 64 KB
    const int t    = threadIdx.x;
    const int lane = t & 63;
    const int w    = t >> 6;
    const int wm   = w >> 1, wn = w & 1;
    const int l15  = lane & 15, kg8 = (lane >> 4) * 8;
    const int mt   = blockIdx.x * 128;

    // ---- stage A once (verified round-6 pattern, row stride now 256) ----
    {
        const int r  = t >> 1;
        const int h2 = t & 1;
        int m  = mt + r;
        int Bi = m / NTOK, n = m - Bi * NTOK;
        int l  = n / 49,   ww = n - l * 49;
        int xx = Bi >> 4,  yy = Bi & 15;
        const float* arow = x + (size_t)((((l * 16 + xx) * 16 + yy) * 49 + ww) << 8) + h2 * 32;
#pragma unroll
        for (int kk = 0; kk < 256; kk += 64) {
#pragma unroll
            for (int c = 0; c < 4; ++c) {
                float4 f0 = *(const float4*)(arow + kk + c * 8);
                float4 f1 = *(const float4*)(arow + kk + c * 8 + 4);
                int idx = (r * 256 + kk + h2 * 32 + c * 8) ^ ((r & 7) << 3);
                *(bf16x8*)&As[idx] = cvt8(f0, f1);
            }
        }
    }
    __syncthreads();   // the only barrier

    const float scale = 0.17677669529663687f;  // dh^-0.5
    const int rq   = lane >> 4;
    const int cidx = lane & 15;

    for (int ct = 0; ct < 6; ++ct) {
        const int cb = ct * 128;
        const ushort_t* brow[4];
#pragma unroll
        for (int fj = 0; fj < 4; ++fj) {
            int nn = cb + wn * 64 + fj * 16 + l15;
            brow[fj] = wqkvT + (size_t)nn * 256 + kg8;
        }

        f32x4 acc[4][4];
#pragma unroll
        for (int i = 0; i < 4; ++i)
#pragma unroll
            for (int j = 0; j < 4; ++j) acc[i][j] = (f32x4){0.f, 0.f, 0.f, 0.f};

#pragma unroll 2
        for (int kk = 0; kk < 256; kk += 32) {
            bf16x8 af[4], bfr[4];
#pragma unroll
            for (int fi = 0; fi < 4; ++fi) {
                int rr  = wm * 64 + fi * 16 + l15;
                int idx = (rr * 256 + kk + kg8) ^ ((rr & 7) << 3);
                af[fi] = *(const bf16x8*)&As[idx];
            }
#pragma unroll
            for (int fj = 0; fj < 4; ++fj)
                bfr[fj] = *(const bf16x8*)(brow[fj] + kk);
#pragma unroll
            for (int fi = 0; fi < 4; ++fi)
#pragma unroll
                for (int fj = 0; fj < 4; ++fj)
                    acc[fi][fj] = __builtin_amdgcn_mfma_f32_16x16x32_bf16(
                        af[fi], bfr[fj], acc[fi][fj], 0, 0, 0);
        }

        // epilogue (verified scatter) for this column tile
#pragma unroll
        for (int fi = 0; fi < 4; ++fi) {
#pragma unroll
            for (int reg = 0; reg < 4; ++reg) {
                int mm  = mt + wm * 64 + fi * 16 + rq * 4 + reg;
                int Bi2 = mm / NTOK, n2 = mm - Bi2 * NTOK;
#pragma unroll
                for (int fj = 0; fj < 4; ++fj) {
                    int c     = cb + wn * 64 + fj * 16 + cidx;
                    int which = c >> 8;
                    int rr    = c & 255;
                    int hh    = rr >> 5, di = rr & 31;
                    int bhi   = Bi2 * 8 + hh;
                    if (which == 0) {
                        qb[((size_t)bhi * NTOK + n2) * 32 + di] = f2bf(acc[fi][fj][reg] * scale);
                    } else if (which == 1) {
                        kb[((size_t)bhi * NTOK + n2) * 32 + di] = f2bf(acc[fi][fj][reg]);
                    } else {
                        vt[((size_t)bhi * 32 + di) * NTOK + n2] = f2bf(acc[fi][fj][reg]);
                    }
                }
            }
        }
    }
}

// ---------------- Kernel C: MFMA flash attention (unchanged, verified) ---
#define S_KS 40
#define S_VS 328
#define S_PS 40
__global__ __launch_bounds__(256) void attn_mfma(ushort_t* __restrict__ qb,
                                                 const ushort_t* __restrict__ kb,
                                                 const ushort_t* __restrict__ vt,
                                                 const float* __restrict__ biasQ) {
    __shared__ ushort_t ks[320 * S_KS];
    __shared__ ushort_t vs[32 * S_VS];
    __shared__ ushort_t ps[4 * 16 * S_PS];
    const int qt = blockIdx.x, bh = blockIdx.y, h = bh & 7;
    const int tid = threadIdx.x;

    const unsigned int* ksrc = (const unsigned int*)(kb + (size_t)bh * NTOK * 32);
    for (int t = tid; t < 294 * 16; t += 256) {
        int r = t >> 4, i = t & 15;
        *(unsigned int*)&ks[r * S_KS + 2 * i] = ksrc[t];
    }
    for (int t = tid; t < 26 * 16; t += 256) {
        int r = 294 + (t >> 4), i = t & 15;
        *(unsigned int*)&ks[r * S_KS + 2 * i] = 0u;
    }
    const unsigned int* vsrc = (const unsigned int*)(vt + (size_t)bh * 32 * NTOK);
    for (int t = tid; t < 32 * 147; t += 256) {
        int d = t / 147, i = t - d * 147;
        *(unsigned int*)&vs[d * S_VS + 2 * i] = vsrc[t];
    }
    for (int t = tid; t < 32 * 17; t += 256) {
        int d = t / 17, i = 147 + (t - d * 17);
        *(unsigned int*)&vs[d * S_VS + 2 * i] = 0u;
    }
    __syncthreads();

    const int wave = tid >> 6, lane = tid & 63;
    const int c = lane & 15, g = lane >> 4;
    const int q0 = qt * 128 + wave * 32;

    bf16x8 qf[2];
#pragma unroll
    for (int qs = 0; qs < 2; ++qs) {
        int qa = q0 + qs * 16 + c; if (qa > 293) qa = 293;
        qf[qs] = *(const bf16x8*)&qb[((size_t)bh * NTOK + qa) * 32 + 8 * g];
    }
    f32x4 acc_o[2][2];
    float psum[2][4];
#pragma unroll
    for (int qs = 0; qs < 2; ++qs) {
#pragma unroll
        for (int hf = 0; hf < 2; ++hf) acc_o[qs][hf] = (f32x4){0.f, 0.f, 0.f, 0.f};
#pragma unroll
        for (int rg = 0; rg < 4; ++rg) psum[qs][rg] = 0.f;
    }
    ushort_t* pw = ps + wave * 16 * S_PS;
    const float* bbase = biasQ + (size_t)h * NN;

    for (int kt = 0; kt < 10; ++kt) {
        const int kbase = kt * 32;
        bf16x8 kf[2], vf[2];
#pragma unroll
        for (int ksub = 0; ksub < 2; ++ksub)
            kf[ksub] = *(const bf16x8*)&ks[(kbase + ksub * 16 + c) * S_KS + 8 * g];
#pragma unroll
        for (int hf = 0; hf < 2; ++hf)
            vf[hf] = *(const bf16x8*)&vs[(hf * 16 + c) * S_VS + kbase + 8 * g];

#pragma unroll
        for (int qs = 0; qs < 2; ++qs) {
            f32x4 s0 = __builtin_amdgcn_mfma_f32_16x16x32_bf16(
                qf[qs], kf[0], (f32x4){0.f, 0.f, 0.f, 0.f}, 0, 0, 0);
            f32x4 s1 = __builtin_amdgcn_mfma_f32_16x16x32_bf16(
                qf[qs], kf[1], (f32x4){0.f, 0.f, 0.f, 0.f}, 0, 0, 0);
            const int qrb = q0 + qs * 16 + g * 4;
#pragma unroll
            for (int rg = 0; rg < 4; ++rg) {
                int qa = qrb + rg; if (qa > 293) qa = 293;
                const float* bp = bbase + (size_t)qa * NTOK;
#pragma unroll
                for (int ksub = 0; ksub < 2; ++ksub) {
                    int ka = kbase + ksub * 16 + c;
                    int kc = ka > 293 ? 293 : ka;
                    float bias = (ka < NTOK) ? bp[kc] : -1e4f;
                    float s = (ksub ? s1[rg] : s0[rg]) + bias;
                    float p = __expf(s);
                    psum[qs][rg] += p;
                    pw[(g * 4 + rg) * S_PS + ksub * 16 + c] = f2bf(p);
                }
            }
            bf16x8 pa = *(const bf16x8*)&pw[c * S_PS + 8 * g];
#pragma unroll
            for (int hf = 0; hf < 2; ++hf)
                acc_o[qs][hf] = __builtin_amdgcn_mfma_f32_16x16x32_bf16(
                    pa, vf[hf], acc_o[qs][hf], 0, 0, 0);
        }
    }

#pragma unroll
    for (int qs = 0; qs < 2; ++qs)
#pragma unroll
        for (int rg = 0; rg < 4; ++rg) {
            float v = psum[qs][rg];
            v += __shfl_xor(v, 1); v += __shfl_xor(v, 2);
            v += __shfl_xor(v, 4); v += __shfl_xor(v, 8);
            psum[qs][rg] = 1.0f / v;
        }

#pragma unroll
    for (int qs = 0; qs < 2; ++qs) {
        const int qrb = q0 + qs * 16 + g * 4;
#pragma unroll
        for (int rg = 0; rg < 4; ++rg) {
            int qa = qrb + rg;
            if (qa < NTOK) {
#pragma unroll
                for (int hf = 0; hf < 2; ++hf) {
                    float val = acc_o[qs][hf][rg] * psum[qs][rg];
                    qb[((size_t)bh * NTOK + qa) * 32 + hf * 16 + c] = f2bf(val);
                }
            }
        }
    }
}

// ---------------- Kernel D: LDS-free out projection (unchanged r6) -------
__global__ __launch_bounds__(256) void out_gemm_mfma2(const ushort_t* __restrict__ ob,
                                                      const ushort_t* __restrict__ woutT,
                                                      float* __restrict__ out) {
    const int t    = threadIdx.x;
    const int lane = t & 63;
    const int w    = t >> 6;
    const int wm   = w >> 1, wn = w & 1;
    const int l15  = lane & 15, kg8 = (lane >> 4) * 8;
    const int cb   = blockIdx.x * 128;
    const int mt   = blockIdx.y * 128;

    const ushort_t* abase[4];
#pragma unroll
    for (int fi = 0; fi < 4; ++fi) {
        int m  = mt + wm * 64 + fi * 16 + l15;
        int Bi = m / NTOK, n = m - Bi * NTOK;
        abase[fi] = ob + ((size_t)(Bi * 8) * NTOK + n) * 32 + kg8;
    }
    const ushort_t* brow[4];
#pragma unroll
    for (int fj = 0; fj < 4; ++fj) {
        int nn = cb + wn * 64 + fj * 16 + l15;
        brow[fj] = woutT + (size_t)nn * 256 + kg8;
    }

    f32x4 acc[4][4];
#pragma unroll
    for (int i = 0; i < 4; ++i)
#pragma unroll
        for (int j = 0; j < 4; ++j) acc[i][j] = (f32x4){0.f, 0.f, 0.f, 0.f};

#pragma unroll 2
    for (int kk = 0; kk < 256; kk += 32) {
        const int hstep = kk >> 5;
        bf16x8 af[4], bfr[4];
#pragma unroll
        for (int fi = 0; fi < 4; ++fi)
            af[fi] = *(const bf16x8*)(abase[fi] + (size_t)hstep * NTOK * 32);
#pragma unroll
        for (int fj = 0; fj < 4; ++fj)
            bfr[fj] = *(const bf16x8*)(brow[fj] + kk);
#pragma unroll
        for (int fi = 0; fi < 4; ++fi)
#pragma unroll
            for (int fj = 0; fj < 4; ++fj)
                acc[fi][fj] = __builtin_amdgcn_mfma_f32_16x16x32_bf16(
                    af[fi], bfr[fj], acc[fi][fj], 0, 0, 0);
    }

    const int rq   = lane >> 4;
    const int cidx = lane & 15;
#pragma unroll
    for (int fi = 0; fi < 4; ++fi) {
#pragma unroll
        for (int reg = 0; reg < 4; ++reg) {
            int mm  = mt + wm * 64 + fi * 16 + rq * 4 + reg;
            int Bi2 = mm / NTOK, n2 = mm - Bi2 * NTOK;
            int l2  = n2 / 49,   w2 = n2 - l2 * 49;
            int xx2 = Bi2 >> 4,  yy2 = Bi2 & 15;
            float* orow = out + (size_t)((((l2 * 16 + xx2) * 16 + yy2) * 49 + w2) << 8);
#pragma unroll
            for (int fj = 0; fj < 4; ++fj) {
                int c = cb + wn * 64 + fj * 16 + cidx;
                orow[c] = acc[fi][fj][reg];
            }
        }
    }
}

extern "C" void kernel_launch(void* const* d_in, const int* in_sizes, int n_in,
                              void* d_out, int out_size, void* d_ws, size_t ws_size,
                              hipStream_t stream) {
    const float* x     = (const float*)d_in[0];
    const float* wqkv  = (const float*)d_in[1];
    const float* wout  = (const float*)d_in[2];
    const float* table = (const float*)d_in[3];
    const int*   rel   = (const int*)d_in[4];
    float* out = (float*)d_out;

    ushort_t* qb    = (ushort_t*)d_ws;
    ushort_t* kb    = qb + USN;
    ushort_t* vt    = kb + USN;
    float*    biasQ = (float*)(vt + USN);         // 8*NN floats
    ushort_t* wqkvT = (ushort_t*)(biasQ + 8 * NN); // 768*256
    ushort_t* woutT = wqkvT + 768 * 256;           // 256*256

    hipLaunchKernelGGL(bias_expand, dim3((NN + 255) / 256), dim3(256), 0, stream,
                       table, rel, biasQ);
    hipLaunchKernelGGL(wt_prep, dim3((768 * 256 + 256 * 256) / 256), dim3(256), 0, stream,
                       wqkv, wout, wqkvT, woutT);
    hipLaunchKernelGGL(qkv_gemm_mfma3, dim3(588), dim3(256), 0, stream,
                       x, wqkvT, qb, kb, vt);
    hipLaunchKernelGGL(attn_mfma, dim3(3, 2048), dim3(256), 0, stream,
                       qb, kb, vt, biasQ);
    hipLaunchKernelGGL(out_gemm_mfma2, dim3(2, 588), dim3(256), 0, stream,
                       qb, woutT, out);
}

// Round 10
// 441.503 us; speedup vs baseline: 1.1079x; 1.0753x over previous
//
#include <hip/hip_runtime.h>
#include <hip/hip_bf16.h>

// Problem constants
#define NTOK 294                    // AGENT*WIN*WIN = 6*49
#define NB   256                    // X*Y = 16*16
#define NN   (NTOK*NTOK)            // 86436
#define ROWS_M (NB*NTOK)            // 75264
#define USN  19267584ULL            // 2048*294*32 ushorts (= 75264*256 too)
// ws: qb | kb | vb | xb (bf16, USN each) | biasQ f32 (8*NN) | wqkvT | woutT

typedef __bf16 bf16x8 __attribute__((ext_vector_type(8)));
typedef float  f32x4  __attribute__((ext_vector_type(4)));
typedef unsigned short ushort_t;

__device__ inline unsigned short f2bf(float f) {      // RNE fp32 -> bf16
    unsigned int u = __float_as_uint(f);
    return (unsigned short)((u + 0x7FFFu + ((u >> 16) & 1u)) >> 16);
}

__device__ inline bf16x8 cvt8(float4 a, float4 b) {
    bf16x8 r;
    r[0] = (__bf16)a.x; r[1] = (__bf16)a.y; r[2] = (__bf16)a.z; r[3] = (__bf16)a.w;
    r[4] = (__bf16)b.x; r[5] = (__bf16)b.y; r[6] = (__bf16)b.z; r[7] = (__bf16)b.w;
    return r;
}

// ---------------- Kernel A: bias expand to [h][q][k] fp32 ----------------
__global__ void bias_expand(const float* __restrict__ table,
                            const int* __restrict__ rel,
                            float* __restrict__ biasQ) {
    int t = blockIdx.x * 256 + threadIdx.x;   // t = i*294 + j (q-major)
    if (t >= NN) return;
    int idx = rel[t];
    const float* src = table + idx * 8;
#pragma unroll
    for (int h = 0; h < 8; ++h)
        biasQ[h * NN + t] = src[h];
}

// ---------------- Kernel A2: weight transposes to bf16 [n][k] ------------
__global__ void wt_prep(const float* __restrict__ wqkv,
                        const float* __restrict__ wout,
                        ushort_t* __restrict__ wqkvT,
                        ushort_t* __restrict__ woutT) {
    int t = blockIdx.x * 256 + threadIdx.x;
    if (t < 768 * 256) {
        int n = t >> 8, k = t & 255;
        wqkvT[t] = f2bf(wqkv[k * 768 + n]);
    } else {
        int u = t - 768 * 256;
        int n = u >> 8, k = u & 255;
        woutT[u] = f2bf(wout[k * 256 + n]);
    }
}

// ---------------- Kernel A3: x fp32 -> bf16 (same layout; 38.5 MB, L3-fit)
__global__ void x_cvt(const float* __restrict__ x, ushort_t* __restrict__ xb) {
    const size_t total = USN / 8;             // 2,408,448 groups of 8
    size_t stride = (size_t)gridDim.x * 256;
    for (size_t i = blockIdx.x * 256 + threadIdx.x; i < total; i += stride) {
        float4 f0 = ((const float4*)x)[2 * i];
        float4 f1 = ((const float4*)x)[2 * i + 1];
        ((bf16x8*)xb)[i] = cvt8(f0, f1);
    }
}

// ---------------- Kernel B: LDS-free bf16 QKV projection (MFMA) ----------
// grid (588 row-tiles FASTEST, 6 col-tiles). A-frags read directly from
// L3-resident xb (38.5 MB); B-frags from L2-resident wqkvT (393 KB).
// No LDS, no barriers, no cvt in the loop. q/k/v all written [bh][n][32].
__global__ __launch_bounds__(256) void qkv_gemm_mfma4(const ushort_t* __restrict__ xb,
                                                      const ushort_t* __restrict__ wqkvT,
                                                      ushort_t* __restrict__ qb,
                                                      ushort_t* __restrict__ kb,
                                                      ushort_t* __restrict__ vb) {
    const int t    = threadIdx.x;
    const int lane = t & 63;
    const int w    = t >> 6;
    const int wm   = w >> 1, wn = w & 1;
    const int l15  = lane & 15, kg8 = (lane >> 4) * 8;
    const int mt   = blockIdx.x * 128;
    const int cb   = blockIdx.y * 128;

    const ushort_t* arow[4];
#pragma unroll
    for (int fi = 0; fi < 4; ++fi) {
        int m  = mt + wm * 64 + fi * 16 + l15;
        int Bi = m / NTOK, n = m - Bi * NTOK;
        int l  = n / 49,   ww = n - l * 49;
        int xx = Bi >> 4,  yy = Bi & 15;
        arow[fi] = xb + ((size_t)((((l * 16 + xx) * 16 + yy) * 49 + ww)) << 8) + kg8;
    }
    const ushort_t* brow[4];
#pragma unroll
    for (int fj = 0; fj < 4; ++fj) {
        int nn = cb + wn * 64 + fj * 16 + l15;
        brow[fj] = wqkvT + (size_t)nn * 256 + kg8;
    }

    f32x4 acc[4][4];
#pragma unroll
    for (int i = 0; i < 4; ++i)
#pragma unroll
        for (int j = 0; j < 4; ++j) acc[i][j] = (f32x4){0.f, 0.f, 0.f, 0.f};

#pragma unroll 2
    for (int kk = 0; kk < 256; kk += 32) {
        bf16x8 af[4], bfr[4];
#pragma unroll
        for (int fi = 0; fi < 4; ++fi)
            af[fi] = *(const bf16x8*)(arow[fi] + kk);
#pragma unroll
        for (int fj = 0; fj < 4; ++fj)
            bfr[fj] = *(const bf16x8*)(brow[fj] + kk);
#pragma unroll
        for (int fi = 0; fi < 4; ++fi)
#pragma unroll
            for (int fj = 0; fj < 4; ++fj)
                acc[fi][fj] = __builtin_amdgcn_mfma_f32_16x16x32_bf16(
                    af[fi], bfr[fj], acc[fi][fj], 0, 0, 0);
    }

    // epilogue: q(scaled)/k/v all coalesced [bh][n][32] bf16
    const float scale = 0.17677669529663687f;  // dh^-0.5
    const int rq   = lane >> 4;
    const int cidx = lane & 15;
#pragma unroll
    for (int fi = 0; fi < 4; ++fi) {
#pragma unroll
        for (int reg = 0; reg < 4; ++reg) {
            int mm  = mt + wm * 64 + fi * 16 + rq * 4 + reg;
            int Bi2 = mm / NTOK, n2 = mm - Bi2 * NTOK;
#pragma unroll
            for (int fj = 0; fj < 4; ++fj) {
                int c     = cb + wn * 64 + fj * 16 + cidx;
                int which = c >> 8;
                int rr    = c & 255;
                int hh    = rr >> 5, di = rr & 31;
                int bhi   = Bi2 * 8 + hh;
                ushort_t* dst = which == 0 ? qb : (which == 1 ? kb : vb);
                float vvv = acc[fi][fj][reg] * (which == 0 ? scale : 1.0f);
                dst[((size_t)bhi * NTOK + n2) * 32 + di] = f2bf(vvv);
            }
        }
    }
}

// ---------------- Kernel C: MFMA flash attention ------------------------
// Compute loop byte-identical to the verified round-6 version. Only change:
// V staging now transposes [n][32] -> vs[32][328] via __byte_perm pairs
// (vs content identical to before: vs[d*328+n] = v[n][d]).
#define S_KS 40
#define S_VS 328
#define S_PS 40
__global__ __launch_bounds__(256) void attn_mfma(ushort_t* __restrict__ qb,
                                                 const ushort_t* __restrict__ kb,
                                                 const ushort_t* __restrict__ vb,
                                                 const float* __restrict__ biasQ) {
    __shared__ ushort_t ks[320 * S_KS];
    __shared__ ushort_t vs[32 * S_VS];
    __shared__ ushort_t ps[4 * 16 * S_PS];
    const int qt = blockIdx.x, bh = blockIdx.y, h = bh & 7;
    const int tid = threadIdx.x;

    const unsigned int* ksrc = (const unsigned int*)(kb + (size_t)bh * NTOK * 32);
    for (int t = tid; t < 294 * 16; t += 256) {
        int r = t >> 4, i = t & 15;
        *(unsigned int*)&ks[r * S_KS + 2 * i] = ksrc[t];
    }
    for (int t = tid; t < 26 * 16; t += 256) {
        int r = 294 + (t >> 4), i = t & 15;
        *(unsigned int*)&ks[r * S_KS + 2 * i] = 0u;
    }
    // V transpose-staging: rows 2r2,2r2+1 dword i -> vs[(2i)(..)] / vs[(2i+1)..]
    const unsigned int* vsrc = (const unsigned int*)(vb + (size_t)bh * NTOK * 32);
    for (int t = tid; t < 147 * 16; t += 256) {
        int r2 = t >> 4;                       // 0..146 -> rows 2r2, 2r2+1
        int i  = t & 15;                       // dword -> d = 2i, 2i+1
        unsigned int A = vsrc[(2 * r2) * 16 + i];
        unsigned int B = vsrc[(2 * r2 + 1) * 16 + i];
        *(unsigned int*)&vs[(2 * i) * S_VS + 2 * r2]     = __byte_perm(A, B, 0x5410);
        *(unsigned int*)&vs[(2 * i + 1) * S_VS + 2 * r2] = __byte_perm(A, B, 0x7632);
    }
    for (int t = tid; t < 32 * 17; t += 256) {
        int d = t / 17, i = 147 + (t - d * 17);
        *(unsigned int*)&vs[d * S_VS + 2 * i] = 0u;
    }
    __syncthreads();

    const int wave = tid >> 6, lane = tid & 63;
    const int c = lane & 15, g = lane >> 4;
    const int q0 = qt * 128 + wave * 32;

    bf16x8 qf[2];
#pragma unroll
    for (int qs = 0; qs < 2; ++qs) {
        int qa = q0 + qs * 16 + c; if (qa > 293) qa = 293;
        qf[qs] = *(const bf16x8*)&qb[((size_t)bh * NTOK + qa) * 32 + 8 * g];
    }
    f32x4 acc_o[2][2];
    float psum[2][4];
#pragma unroll
    for (int qs = 0; qs < 2; ++qs) {
#pragma unroll
        for (int hf = 0; hf < 2; ++hf) acc_o[qs][hf] = (f32x4){0.f, 0.f, 0.f, 0.f};
#pragma unroll
        for (int rg = 0; rg < 4; ++rg) psum[qs][rg] = 0.f;
    }
    ushort_t* pw = ps + wave * 16 * S_PS;
    const float* bbase = biasQ + (size_t)h * NN;

    for (int kt = 0; kt < 10; ++kt) {
        const int kbase = kt * 32;
        bf16x8 kf[2], vf[2];
#pragma unroll
        for (int ksub = 0; ksub < 2; ++ksub)
            kf[ksub] = *(const bf16x8*)&ks[(kbase + ksub * 16 + c) * S_KS + 8 * g];
#pragma unroll
        for (int hf = 0; hf < 2; ++hf)
            vf[hf] = *(const bf16x8*)&vs[(hf * 16 + c) * S_VS + kbase + 8 * g];

#pragma unroll
        for (int qs = 0; qs < 2; ++qs) {
            f32x4 s0 = __builtin_amdgcn_mfma_f32_16x16x32_bf16(
                qf[qs], kf[0], (f32x4){0.f, 0.f, 0.f, 0.f}, 0, 0, 0);
            f32x4 s1 = __builtin_amdgcn_mfma_f32_16x16x32_bf16(
                qf[qs], kf[1], (f32x4){0.f, 0.f, 0.f, 0.f}, 0, 0, 0);
            const int qrb = q0 + qs * 16 + g * 4;
#pragma unroll
            for (int rg = 0; rg < 4; ++rg) {
                int qa = qrb + rg; if (qa > 293) qa = 293;
                const float* bp = bbase + (size_t)qa * NTOK;
#pragma unroll
                for (int ksub = 0; ksub < 2; ++ksub) {
                    int ka = kbase + ksub * 16 + c;
                    int kc = ka > 293 ? 293 : ka;
                    float bias = (ka < NTOK) ? bp[kc] : -1e4f;
                    float s = (ksub ? s1[rg] : s0[rg]) + bias;
                    float p = __expf(s);
                    psum[qs][rg] += p;
                    pw[(g * 4 + rg) * S_PS + ksub * 16 + c] = f2bf(p);
                }
            }
            bf16x8 pa = *(const bf16x8*)&pw[c * S_PS + 8 * g];
#pragma unroll
            for (int hf = 0; hf < 2; ++hf)
                acc_o[qs][hf] = __builtin_amdgcn_mfma_f32_16x16x32_bf16(
                    pa, vf[hf], acc_o[qs][hf], 0, 0, 0);
        }
    }

#pragma unroll
    for (int qs = 0; qs < 2; ++qs)
#pragma unroll
        for (int rg = 0; rg < 4; ++rg) {
            float v = psum[qs][rg];
            v += __shfl_xor(v, 1); v += __shfl_xor(v, 2);
            v += __shfl_xor(v, 4); v += __shfl_xor(v, 8);
            psum[qs][rg] = 1.0f / v;
        }

#pragma unroll
    for (int qs = 0; qs < 2; ++qs) {
        const int qrb = q0 + qs * 16 + g * 4;
#pragma unroll
        for (int rg = 0; rg < 4; ++rg) {
            int qa = qrb + rg;
            if (qa < NTOK) {
#pragma unroll
                for (int hf = 0; hf < 2; ++hf) {
                    float val = acc_o[qs][hf][rg] * psum[qs][rg];
                    qb[((size_t)bh * NTOK + qa) * 32 + hf * 16 + c] = f2bf(val);
                }
            }
        }
    }
}

// ---------------- Kernel D: LDS-free out projection (grid x=rows fastest) -
__global__ __launch_bounds__(256) void out_gemm_mfma2(const ushort_t* __restrict__ ob,
                                                      const ushort_t* __restrict__ woutT,
                                                      float* __restrict__ out) {
    const int t    = threadIdx.x;
    const int lane = t & 63;
    const int w    = t >> 6;
    const int wm   = w >> 1, wn = w & 1;
    const int l15  = lane & 15, kg8 = (lane >> 4) * 8;
    const int mt   = blockIdx.x * 128;
    const int cb   = blockIdx.y * 128;

    const ushort_t* abase[4];
#pragma unroll
    for (int fi = 0; fi < 4; ++fi) {
        int m  = mt + wm * 64 + fi * 16 + l15;
        int Bi = m / NTOK, n = m - Bi * NTOK;
        abase[fi] = ob + ((size_t)(Bi * 8) * NTOK + n) * 32 + kg8;
    }
    const ushort_t* brow[4];
#pragma unroll
    for (int fj = 0; fj < 4; ++fj) {
        int nn = cb + wn * 64 + fj * 16 + l15;
        brow[fj] = woutT + (size_t)nn * 256 + kg8;
    }

    f32x4 acc[4][4];
#pragma unroll
    for (int i = 0; i < 4; ++i)
#pragma unroll
        for (int j = 0; j < 4; ++j) acc[i][j] = (f32x4){0.f, 0.f, 0.f, 0.f};

#pragma unroll 2
    for (int kk = 0; kk < 256; kk += 32) {
        const int hstep = kk >> 5;
        bf16x8 af[4], bfr[4];
#pragma unroll
        for (int fi = 0; fi < 4; ++fi)
            af[fi] = *(const bf16x8*)(abase[fi] + (size_t)hstep * NTOK * 32);
#pragma unroll
        for (int fj = 0; fj < 4; ++fj)
            bfr[fj] = *(const bf16x8*)(brow[fj] + kk);
#pragma unroll
        for (int fi = 0; fi < 4; ++fi)
#pragma unroll
            for (int fj = 0; fj < 4; ++fj)
                acc[fi][fj] = __builtin_amdgcn_mfma_f32_16x16x32_bf16(
                    af[fi], bfr[fj], acc[fi][fj], 0, 0, 0);
    }

    const int rq   = lane >> 4;
    const int cidx = lane & 15;
#pragma unroll
    for (int fi = 0; fi < 4; ++fi) {
#pragma unroll
        for (int reg = 0; reg < 4; ++reg) {
            int mm  = mt + wm * 64 + fi * 16 + rq * 4 + reg;
            int Bi2 = mm / NTOK, n2 = mm - Bi2 * NTOK;
            int l2  = n2 / 49,   w2 = n2 - l2 * 49;
            int xx2 = Bi2 >> 4,  yy2 = Bi2 & 15;
            float* orow = out + (size_t)((((l2 * 16 + xx2) * 16 + yy2) * 49 + w2) << 8);
#pragma unroll
            for (int fj = 0; fj < 4; ++fj) {
                int c = cb + wn * 64 + fj * 16 + cidx;
                orow[c] = acc[fi][fj][reg];
            }
        }
    }
}

extern "C" void kernel_launch(void* const* d_in, const int* in_sizes, int n_in,
                              void* d_out, int out_size, void* d_ws, size_t ws_size,
                              hipStream_t stream) {
    const float* x     = (const float*)d_in[0];
    const float* wqkv  = (const float*)d_in[1];
    const float* wout  = (const float*)d_in[2];
    const float* table = (const float*)d_in[3];
    const int*   rel   = (const int*)d_in[4];
    float* out = (float*)d_out;

    ushort_t* qb    = (ushort_t*)d_ws;
    ushort_t* kb    = qb + USN;
    ushort_t* vb    = kb + USN;
    ushort_t* xb    = vb + USN;
    float*    biasQ = (float*)(xb + USN);          // 8*NN floats
    ushort_t* wqkvT = (ushort_t*)(biasQ + 8 * NN); // 768*256
    ushort_t* woutT = wqkvT + 768 * 256;           // 256*256

    hipLaunchKernelGGL(bias_expand, dim3((NN + 255) / 256), dim3(256), 0, stream,
                       table, rel, biasQ);
    hipLaunchKernelGGL(wt_prep, dim3((768 * 256 + 256 * 256) / 256), dim3(256), 0, stream,
                       wqkv, wout, wqkvT, woutT);
    hipLaunchKernelGGL(x_cvt, dim3(2048), dim3(256), 0, stream, x, xb);
    hipLaunchKernelGGL(qkv_gemm_mfma4, dim3(588, 6), dim3(256), 0, stream,
                       xb, wqkvT, qb, kb, vb);
    hipLaunchKernelGGL(attn_mfma, dim3(3, 2048), dim3(256), 0, stream,
                       qb, kb, vb, biasQ);
    hipLaunchKernelGGL(out_gemm_mfma2, dim3(588, 2), dim3(256), 0, stream,
                       qb, woutT, out);
}